// Round 1
// baseline (112.159 us; speedup 1.0000x reference)
//
#include <hip/hip_runtime.h>
#include <math.h>

#define A_CUBIC (-0.75f)
#define NB 2
#define NC 3
#define HH 144
#define NPB 2304      // patches per batch (48*48)
#define GG 14460      // database patches per batch
#define DD 27
#define DP 28         // padded row stride
#define GSPLIT 16
#define GTILE 904     // ceil(14460/16)

__constant__ int c_seg_start[15] = {0,2209,2738,2859,5068,5597,5718,7927,8456,8577,10786,11315,11436,13740,14316};
__constant__ int c_seg_gw[15]    = {47,23,11, 47,23,11, 47,23,11, 47,23,11, 48,24,12};
__constant__ int c_seg_oy[15]    = {1,1,1, 1,1,1, 2,2,2, 2,2,2, 0,0,0};
__constant__ int c_seg_ox[15]    = {1,1,1, 2,2,2, 1,1,1, 2,2,2, 0,0,0};
__constant__ int c_seg_src[15]   = {0,1,2, 0,1,2, 0,1,2, 0,1,2, 0,1,2};

__device__ __forceinline__ float cubicw(float t) {
    float at = fabsf(t);
    if (at <= 1.0f) return ((A_CUBIC + 2.0f) * at - (A_CUBIC + 3.0f)) * at * at + 1.0f;
    if (at < 2.0f)  return A_CUBIC * (((at - 5.0f) * at + 8.0f) * at - 4.0f);
    return 0.0f;
}

// K1: bicubic downscale tar -> s1 (72x72) and s2 (36x36). align_corners=True, clamp.
__global__ void bicubic_k(const float* __restrict__ tar, float* __restrict__ s1,
                          float* __restrict__ s2) {
    int t = blockIdx.x * 256 + threadIdx.x;
    const int total1 = NB * NC * 72 * 72;
    const int total2 = NB * NC * 36 * 36;
    float* dst; int O; int idx;
    if (t < total1)              { dst = s1; O = 72; idx = t; }
    else if (t < total1+total2)  { dst = s2; O = 36; idx = t - total1; }
    else return;
    int x  = idx % O;
    int y  = (idx / O) % O;
    int bc = idx / (O * O);
    const float* src = tar + (size_t)bc * HH * HH;
    float scale = (float)(143.0 / (double)(O - 1));
    float fy = (float)y * scale;
    float iyf = floorf(fy); float fry = fy - iyf; int iy = (int)iyf;
    float fx = (float)x * scale;
    float ixf = floorf(fx); float frx = fx - ixf; int ix = (int)ixf;
    float wy[4], wx[4];
    #pragma unroll
    for (int d = 0; d < 4; ++d) {
        wy[d] = cubicw(fry - (float)(d - 1));
        wx[d] = cubicw(frx - (float)(d - 1));
    }
    float acc = 0.0f;
    #pragma unroll
    for (int dx = 0; dx < 4; ++dx) {
        int cx = min(max(ix - 1 + dx, 0), HH - 1);
        float inner = 0.0f;
        #pragma unroll
        for (int dy = 0; dy < 4; ++dy) {
            int cy = min(max(iy - 1 + dy, 0), HH - 1);
            inner += wy[dy] * src[cy * HH + cx];
        }
        acc += wx[dx] * inner;
    }
    dst[idx] = acc;
}

// K2: build gf database rows [B*G][28] + gn [B*G]
__global__ void build_gf_k(const float* __restrict__ tar, const float* __restrict__ s1,
                           const float* __restrict__ s2, float* __restrict__ gf,
                           float* __restrict__ gn) {
    int t = blockIdx.x * 256 + threadIdx.x;
    if (t >= NB * GG) return;
    int b = t / GG, g = t % GG;
    int s = 0;
    #pragma unroll
    for (int k = 1; k < 15; ++k) if (g >= c_seg_start[k]) s = k;
    int p  = g - c_seg_start[s];
    int gw = c_seg_gw[s];
    int hc = p / gw, wc = p % gw;
    int oy = c_seg_oy[s], ox = c_seg_ox[s];
    int srci = c_seg_src[s];
    const float* img; int sz;
    if (srci == 0)      { img = tar; sz = 144; }
    else if (srci == 1) { img = s1;  sz = 72;  }
    else                { img = s2;  sz = 36;  }
    const float* base = img + (size_t)b * NC * sz * sz;
    int y0 = oy + hc * 3, x0 = ox + wc * 3;
    float acc = 0.0f;
    float* row = gf + (size_t)t * DP;
    #pragma unroll
    for (int c = 0; c < 3; ++c)
        #pragma unroll
        for (int dy = 0; dy < 3; ++dy)
            #pragma unroll
            for (int dx = 0; dx < 3; ++dx) {
                float v = base[((size_t)c * sz + y0 + dy) * sz + x0 + dx];
                row[(c * 3 + dy) * 3 + dx] = v;
                acc = fmaf(v, v, acc);
            }
    row[27] = 0.0f;
    gn[t] = acc;
}

// K3: m = unfold(inp) + unfold(tar)  [B*N][28]
__global__ void build_m_k(const float* __restrict__ inp, const float* __restrict__ tar,
                          float* __restrict__ m) {
    int t = blockIdx.x * 256 + threadIdx.x;
    if (t >= NB * NPB) return;
    int b = t / NPB, n = t % NPB;
    int hc = n / 48, wc = n % 48;
    const float* ib = inp + (size_t)b * NC * HH * HH;
    const float* tb = tar + (size_t)b * NC * HH * HH;
    float* row = m + (size_t)t * DP;
    #pragma unroll
    for (int c = 0; c < 3; ++c)
        #pragma unroll
        for (int dy = 0; dy < 3; ++dy)
            #pragma unroll
            for (int dx = 0; dx < 3; ++dx) {
                int off = (c * HH + hc * 3 + dy) * HH + wc * 3 + dx;
                row[(c * 3 + dy) * 3 + dx] = ib[off] + tb[off];
            }
    row[27] = 0.0f;
}

// K4: for each n, partial argmin over a g-tile of score = gn[g] - m.g
__global__ __launch_bounds__(256) void argmin_k(
        const float* __restrict__ gf, const float* __restrict__ gn,
        const float* __restrict__ m, float* __restrict__ pv, int* __restrict__ pi) {
    __shared__ __align__(16) float mlds[64 * DP];
    __shared__ __align__(16) float glds[64 * DP];
    __shared__ float gnlds[64];
    __shared__ float vred[256];
    __shared__ int   ired[256];
    int tid = threadIdx.x;
    int tileN = blockIdx.y;          // 0..71
    int b  = tileN / 36;
    int n0 = (tileN % 36) * 64;
    const float* msrc = m + ((size_t)b * NPB + n0) * DP;
    for (int k = tid; k < 64 * DP; k += 256) mlds[k] = msrc[k];
    __syncthreads();
    int n_loc = tid & 63, gsub = tid >> 6;
    float4 mr[7];
    #pragma unroll
    for (int i = 0; i < 7; ++i) mr[i] = *(const float4*)&mlds[n_loc * DP + i * 4];
    int g0 = blockIdx.x * GTILE;
    int g1 = min(g0 + GTILE, GG);
    const float* gfb = gf + (size_t)b * GG * DP;
    const float* gnb = gn + (size_t)b * GG;
    float bv = 3.0e38f; int bi = 0x7fffffff;
    for (int cg = g0; cg < g1; cg += 64) {
        int nload = min(64, g1 - cg);
        __syncthreads();
        const float* src = gfb + (size_t)cg * DP;
        for (int k = tid; k < nload * DP; k += 256) glds[k] = src[k];
        for (int k = tid; k < nload; k += 256)      gnlds[k] = gnb[cg + k];
        __syncthreads();
        for (int k = gsub; k < nload; k += 4) {
            const float* gr = &glds[k * DP];
            float4 g0v = *(const float4*)&gr[0];
            float4 g1v = *(const float4*)&gr[4];
            float4 g2v = *(const float4*)&gr[8];
            float4 g3v = *(const float4*)&gr[12];
            float4 g4v = *(const float4*)&gr[16];
            float4 g5v = *(const float4*)&gr[20];
            float4 g6v = *(const float4*)&gr[24];
            float acc = 0.0f;
            acc = fmaf(mr[0].x, g0v.x, acc); acc = fmaf(mr[0].y, g0v.y, acc);
            acc = fmaf(mr[0].z, g0v.z, acc); acc = fmaf(mr[0].w, g0v.w, acc);
            acc = fmaf(mr[1].x, g1v.x, acc); acc = fmaf(mr[1].y, g1v.y, acc);
            acc = fmaf(mr[1].z, g1v.z, acc); acc = fmaf(mr[1].w, g1v.w, acc);
            acc = fmaf(mr[2].x, g2v.x, acc); acc = fmaf(mr[2].y, g2v.y, acc);
            acc = fmaf(mr[2].z, g2v.z, acc); acc = fmaf(mr[2].w, g2v.w, acc);
            acc = fmaf(mr[3].x, g3v.x, acc); acc = fmaf(mr[3].y, g3v.y, acc);
            acc = fmaf(mr[3].z, g3v.z, acc); acc = fmaf(mr[3].w, g3v.w, acc);
            acc = fmaf(mr[4].x, g4v.x, acc); acc = fmaf(mr[4].y, g4v.y, acc);
            acc = fmaf(mr[4].z, g4v.z, acc); acc = fmaf(mr[4].w, g4v.w, acc);
            acc = fmaf(mr[5].x, g5v.x, acc); acc = fmaf(mr[5].y, g5v.y, acc);
            acc = fmaf(mr[5].z, g5v.z, acc); acc = fmaf(mr[5].w, g5v.w, acc);
            acc = fmaf(mr[6].x, g6v.x, acc); acc = fmaf(mr[6].y, g6v.y, acc);
            acc = fmaf(mr[6].z, g6v.z, acc); acc = fmaf(mr[6].w, g6v.w, acc);
            float score = gnlds[k] - acc;
            int gidx = cg + k;
            if (score < bv || (score == bv && gidx < bi)) { bv = score; bi = gidx; }
        }
    }
    vred[tid] = bv; ired[tid] = bi;
    __syncthreads();
    if (tid < 64) {
        float v = vred[tid]; int i0 = ired[tid];
        #pragma unroll
        for (int s = 1; s < 4; ++s) {
            float v2 = vred[tid + 64 * s]; int i2 = ired[tid + 64 * s];
            if (v2 < v || (v2 == v && i2 < i0)) { v = v2; i0 = i2; }
        }
        size_t o = ((size_t)b * NPB + n0 + tid) * GSPLIT + blockIdx.x;
        pv[o] = v; pi[o] = i0;
    }
}

// K5: final argmin over g-tiles, gather sel, fold to image, block-partial L1 sums
__global__ void finalize_k(const float* __restrict__ gf, const float* __restrict__ pv,
                           const int* __restrict__ pi, const float* __restrict__ inp,
                           float* __restrict__ out, float* __restrict__ lpart) {
    __shared__ float red[256];
    int t = blockIdx.x * 256 + threadIdx.x;
    float lsum = 0.0f;
    if (t < NB * NPB) {
        int b = t / NPB, n = t % NPB;
        float bv = 3.0e38f; int bi = 0x7fffffff;
        #pragma unroll
        for (int s = 0; s < GSPLIT; ++s) {
            float v = pv[(size_t)t * GSPLIT + s];
            int   i = pi[(size_t)t * GSPLIT + s];
            if (v < bv || (v == bv && i < bi)) { bv = v; bi = i; }
        }
        int hc = n / 48, wc = n % 48;
        const float* grow = gf + ((size_t)b * GG + bi) * DP;
        const float* ib   = inp + (size_t)b * NC * HH * HH;
        float* sel = out + 1 + (size_t)b * NC * HH * HH;
        #pragma unroll
        for (int c = 0; c < 3; ++c)
            #pragma unroll
            for (int dy = 0; dy < 3; ++dy)
                #pragma unroll
                for (int dx = 0; dx < 3; ++dx) {
                    int d = (c * 3 + dy) * 3 + dx;
                    float sv = grow[d];
                    int off = (c * HH + hc * 3 + dy) * HH + wc * 3 + dx;
                    sel[off] = sv;
                    lsum += fabsf(ib[off] - sv);
                }
    }
    red[threadIdx.x] = lsum;
    __syncthreads();
    for (int s = 128; s > 0; s >>= 1) {
        if (threadIdx.x < s) red[threadIdx.x] += red[threadIdx.x + s];
        __syncthreads();
    }
    if (threadIdx.x == 0) lpart[blockIdx.x] = red[0];
}

// K6: scalar loss mean
__global__ void sum_k(const float* __restrict__ lpart, float* __restrict__ out) {
    if (threadIdx.x == 0) {
        float s = 0.0f;
        for (int i = 0; i < 18; ++i) s += lpart[i];
        out[0] = s * (1.0f / 124416.0f);
    }
}

extern "C" void kernel_launch(void* const* d_in, const int* in_sizes, int n_in,
                              void* d_out, int out_size, void* d_ws, size_t ws_size,
                              hipStream_t stream) {
    const float* inp = (const float*)d_in[0];
    const float* tar = (const float*)d_in[1];
    float* out = (float*)d_out;
    float* ws  = (float*)d_ws;

    float* s1 = ws;                       // 31104
    float* s2 = s1 + 31104;               // 7776
    float* gf = s2 + 7776;                // 2*14460*28 = 809760
    float* gn = gf + 809760;              // 28920
    float* m  = gn + 28920;               // 2*2304*28 = 129024
    float* pv = m  + 129024;              // 4608*16 = 73728
    int*   pi = (int*)(pv + 73728);       // 73728
    float* lp = (float*)(pi + 73728);     // 18

    bicubic_k <<<(38880 + 255) / 256, 256, 0, stream>>>(tar, s1, s2);
    build_gf_k<<<(28920 + 255) / 256, 256, 0, stream>>>(tar, s1, s2, gf, gn);
    build_m_k <<<(4608  + 255) / 256, 256, 0, stream>>>(inp, tar, m);
    argmin_k  <<<dim3(GSPLIT, 72), 256, 0, stream>>>(gf, gn, m, pv, pi);
    finalize_k<<<18, 256, 0, stream>>>(gf, pv, pi, inp, out, lp);
    sum_k     <<<1, 64, 0, stream>>>(lp, out);
}

// Round 2
// 108.819 us; speedup vs baseline: 1.0307x; 1.0307x over previous
//
#include <hip/hip_runtime.h>
#include <math.h>

#define A_CUBIC (-0.75f)
#define NB 2
#define NC 3
#define HH 144
#define NPB 2304      // patches per batch (48*48)
#define GG 14460      // database patches per batch
#define DD 27
#define DP 28         // padded row stride; row[27] holds gn (for gf) or -1 (for m)
#define GSPLIT 28
#define GTILE 517     // ceil(14460/28)

__constant__ int c_seg_start[15] = {0,2209,2738,2859,5068,5597,5718,7927,8456,8577,10786,11315,11436,13740,14316};
__constant__ int c_seg_gw[15]    = {47,23,11, 47,23,11, 47,23,11, 47,23,11, 48,24,12};
__constant__ int c_seg_oy[15]    = {1,1,1, 1,1,1, 2,2,2, 2,2,2, 0,0,0};
__constant__ int c_seg_ox[15]    = {1,1,1, 2,2,2, 1,1,1, 2,2,2, 0,0,0};
__constant__ int c_seg_src[15]   = {0,1,2, 0,1,2, 0,1,2, 0,1,2, 0,1,2};

__device__ __forceinline__ float cubicw(float t) {
    float at = fabsf(t);
    if (at <= 1.0f) return ((A_CUBIC + 2.0f) * at - (A_CUBIC + 3.0f)) * at * at + 1.0f;
    if (at < 2.0f)  return A_CUBIC * (((at - 5.0f) * at + 8.0f) * at - 4.0f);
    return 0.0f;
}

// K1: bicubic downscale tar -> s1 (72x72) and s2 (36x36). align_corners=True, clamp.
__global__ void bicubic_k(const float* __restrict__ tar, float* __restrict__ s1,
                          float* __restrict__ s2) {
    int t = blockIdx.x * 256 + threadIdx.x;
    const int total1 = NB * NC * 72 * 72;
    const int total2 = NB * NC * 36 * 36;
    float* dst; int O; int idx;
    if (t < total1)              { dst = s1; O = 72; idx = t; }
    else if (t < total1+total2)  { dst = s2; O = 36; idx = t - total1; }
    else return;
    int x  = idx % O;
    int y  = (idx / O) % O;
    int bc = idx / (O * O);
    const float* src = tar + (size_t)bc * HH * HH;
    float scale = (float)(143.0 / (double)(O - 1));
    float fy = (float)y * scale;
    float iyf = floorf(fy); float fry = fy - iyf; int iy = (int)iyf;
    float fx = (float)x * scale;
    float ixf = floorf(fx); float frx = fx - ixf; int ix = (int)ixf;
    float wy[4], wx[4];
    #pragma unroll
    for (int d = 0; d < 4; ++d) {
        wy[d] = cubicw(fry - (float)(d - 1));
        wx[d] = cubicw(frx - (float)(d - 1));
    }
    float acc = 0.0f;
    #pragma unroll
    for (int dx = 0; dx < 4; ++dx) {
        int cx = min(max(ix - 1 + dx, 0), HH - 1);
        float inner = 0.0f;
        #pragma unroll
        for (int dy = 0; dy < 4; ++dy) {
            int cy = min(max(iy - 1 + dy, 0), HH - 1);
            inner += wy[dy] * src[cy * HH + cx];
        }
        acc += wx[dx] * inner;
    }
    dst[idx] = acc;
}

// K2: build gf database rows [B*G][28]; row[27] = |g|^2
__global__ void build_gf_k(const float* __restrict__ tar, const float* __restrict__ s1,
                           const float* __restrict__ s2, float* __restrict__ gf) {
    int t = blockIdx.x * 256 + threadIdx.x;
    if (t >= NB * GG) return;
    int b = t / GG, g = t % GG;
    int s = 0;
    #pragma unroll
    for (int k = 1; k < 15; ++k) if (g >= c_seg_start[k]) s = k;
    int p  = g - c_seg_start[s];
    int gw = c_seg_gw[s];
    int hc = p / gw, wc = p % gw;
    int oy = c_seg_oy[s], ox = c_seg_ox[s];
    int srci = c_seg_src[s];
    const float* img; int sz;
    if (srci == 0)      { img = tar; sz = 144; }
    else if (srci == 1) { img = s1;  sz = 72;  }
    else                { img = s2;  sz = 36;  }
    const float* base = img + (size_t)b * NC * sz * sz;
    int y0 = oy + hc * 3, x0 = ox + wc * 3;
    float acc = 0.0f;
    float* row = gf + (size_t)t * DP;
    #pragma unroll
    for (int c = 0; c < 3; ++c)
        #pragma unroll
        for (int dy = 0; dy < 3; ++dy)
            #pragma unroll
            for (int dx = 0; dx < 3; ++dx) {
                float v = base[((size_t)c * sz + y0 + dy) * sz + x0 + dx];
                row[(c * 3 + dy) * 3 + dx] = v;
                acc = fmaf(v, v, acc);
            }
    row[27] = acc;
}

// K3: m = unfold(inp) + unfold(tar)  [B*N][28]; row[27] = -1
__global__ void build_m_k(const float* __restrict__ inp, const float* __restrict__ tar,
                          float* __restrict__ m) {
    int t = blockIdx.x * 256 + threadIdx.x;
    if (t >= NB * NPB) return;
    int b = t / NPB, n = t % NPB;
    int hc = n / 48, wc = n % 48;
    const float* ib = inp + (size_t)b * NC * HH * HH;
    const float* tb = tar + (size_t)b * NC * HH * HH;
    float* row = m + (size_t)t * DP;
    #pragma unroll
    for (int c = 0; c < 3; ++c)
        #pragma unroll
        for (int dy = 0; dy < 3; ++dy)
            #pragma unroll
            for (int dx = 0; dx < 3; ++dx) {
                int off = (c * HH + hc * 3 + dy) * HH + wc * 3 + dx;
                row[(c * 3 + dy) * 3 + dx] = ib[off] + tb[off];
            }
    row[27] = -1.0f;
}

// K4: for each n, partial ARGMAX over a g-tile of dot28(m, g) = m.g - gn = -score
__global__ __launch_bounds__(256, 8) void argmin_k(
        const float* __restrict__ gf, const float* __restrict__ m,
        float* __restrict__ pv, int* __restrict__ pi) {
    __shared__ __align__(16) float mlds[64 * DP];
    __shared__ __align__(16) float glds[64 * DP];
    __shared__ float vred[256];
    __shared__ int   ired[256];
    int tid = threadIdx.x;
    int tileN = blockIdx.y;          // 0..71
    int b  = tileN / 36;
    int n0 = (tileN % 36) * 64;
    const float4* msrc = (const float4*)(m + ((size_t)b * NPB + n0) * DP);
    for (int k = tid; k < 64 * 7; k += 256) ((float4*)mlds)[k] = msrc[k];
    __syncthreads();
    int n_loc = tid & 63, gsub = tid >> 6;
    float4 mr[7];
    #pragma unroll
    for (int i = 0; i < 7; ++i) mr[i] = *(const float4*)&mlds[n_loc * DP + i * 4];
    int g0 = blockIdx.x * GTILE;
    int g1 = min(g0 + GTILE, GG);
    const float* gfb = gf + (size_t)b * GG * DP;
    float bv = -3.0e38f; int bi = 0x7fffffff;
    for (int cg = g0; cg < g1; cg += 64) {
        int nload = min(64, g1 - cg);
        __syncthreads();
        const float4* src = (const float4*)(gfb + (size_t)cg * DP);
        int n4 = nload * 7;
        for (int k = tid; k < n4; k += 256) ((float4*)glds)[k] = src[k];
        __syncthreads();
        for (int k = gsub; k < nload; k += 4) {
            const float* gr = &glds[k * DP];
            float4 g0v = *(const float4*)&gr[0];
            float4 g1v = *(const float4*)&gr[4];
            float4 g2v = *(const float4*)&gr[8];
            float4 g3v = *(const float4*)&gr[12];
            float4 g4v = *(const float4*)&gr[16];
            float4 g5v = *(const float4*)&gr[20];
            float4 g6v = *(const float4*)&gr[24];
            float a0 = 0.0f, a1 = 0.0f;
            a0 = fmaf(mr[0].x, g0v.x, a0); a0 = fmaf(mr[0].y, g0v.y, a0);
            a0 = fmaf(mr[0].z, g0v.z, a0); a0 = fmaf(mr[0].w, g0v.w, a0);
            a1 = fmaf(mr[1].x, g1v.x, a1); a1 = fmaf(mr[1].y, g1v.y, a1);
            a1 = fmaf(mr[1].z, g1v.z, a1); a1 = fmaf(mr[1].w, g1v.w, a1);
            a0 = fmaf(mr[2].x, g2v.x, a0); a0 = fmaf(mr[2].y, g2v.y, a0);
            a0 = fmaf(mr[2].z, g2v.z, a0); a0 = fmaf(mr[2].w, g2v.w, a0);
            a1 = fmaf(mr[3].x, g3v.x, a1); a1 = fmaf(mr[3].y, g3v.y, a1);
            a1 = fmaf(mr[3].z, g3v.z, a1); a1 = fmaf(mr[3].w, g3v.w, a1);
            a0 = fmaf(mr[4].x, g4v.x, a0); a0 = fmaf(mr[4].y, g4v.y, a0);
            a0 = fmaf(mr[4].z, g4v.z, a0); a0 = fmaf(mr[4].w, g4v.w, a0);
            a1 = fmaf(mr[5].x, g5v.x, a1); a1 = fmaf(mr[5].y, g5v.y, a1);
            a1 = fmaf(mr[5].z, g5v.z, a1); a1 = fmaf(mr[5].w, g5v.w, a1);
            a0 = fmaf(mr[6].x, g6v.x, a0); a0 = fmaf(mr[6].y, g6v.y, a0);
            a0 = fmaf(mr[6].z, g6v.z, a0); a0 = fmaf(mr[6].w, g6v.w, a0);
            float s = a0 + a1;
            // g strictly increases within a thread -> strict > keeps first max
            if (s > bv) { bv = s; bi = cg + k; }
        }
    }
    vred[tid] = bv; ired[tid] = bi;
    __syncthreads();
    if (tid < 64) {
        float v = vred[tid]; int i0 = ired[tid];
        #pragma unroll
        for (int s = 1; s < 4; ++s) {
            float v2 = vred[tid + 64 * s]; int i2 = ired[tid + 64 * s];
            if (v2 > v || (v2 == v && i2 < i0)) { v = v2; i0 = i2; }
        }
        size_t o = ((size_t)b * NPB + n0 + tid) * GSPLIT + blockIdx.x;
        pv[o] = v; pi[o] = i0;
    }
}

// K5: final argmax over g-tiles, gather sel, fold to image, block-partial L1 sums
__global__ void finalize_k(const float* __restrict__ gf, const float* __restrict__ pv,
                           const int* __restrict__ pi, const float* __restrict__ inp,
                           float* __restrict__ out, float* __restrict__ lpart) {
    __shared__ float red[256];
    int t = blockIdx.x * 256 + threadIdx.x;
    float lsum = 0.0f;
    if (t < NB * NPB) {
        int b = t / NPB, n = t % NPB;
        float bv = -3.0e38f; int bi = 0x7fffffff;
        #pragma unroll
        for (int s = 0; s < GSPLIT; ++s) {
            float v = pv[(size_t)t * GSPLIT + s];
            int   i = pi[(size_t)t * GSPLIT + s];
            if (v > bv || (v == bv && i < bi)) { bv = v; bi = i; }
        }
        int hc = n / 48, wc = n % 48;
        const float* grow = gf + ((size_t)b * GG + bi) * DP;
        const float* ib   = inp + (size_t)b * NC * HH * HH;
        float* sel = out + 1 + (size_t)b * NC * HH * HH;
        #pragma unroll
        for (int c = 0; c < 3; ++c)
            #pragma unroll
            for (int dy = 0; dy < 3; ++dy)
                #pragma unroll
                for (int dx = 0; dx < 3; ++dx) {
                    int d = (c * 3 + dy) * 3 + dx;
                    float sv = grow[d];
                    int off = (c * HH + hc * 3 + dy) * HH + wc * 3 + dx;
                    sel[off] = sv;
                    lsum += fabsf(ib[off] - sv);
                }
    }
    red[threadIdx.x] = lsum;
    __syncthreads();
    for (int s = 128; s > 0; s >>= 1) {
        if (threadIdx.x < s) red[threadIdx.x] += red[threadIdx.x + s];
        __syncthreads();
    }
    if (threadIdx.x == 0) lpart[blockIdx.x] = red[0];
}

// K6: scalar loss mean
__global__ void sum_k(const float* __restrict__ lpart, float* __restrict__ out) {
    if (threadIdx.x == 0) {
        float s = 0.0f;
        for (int i = 0; i < 18; ++i) s += lpart[i];
        out[0] = s * (1.0f / 124416.0f);
    }
}

extern "C" void kernel_launch(void* const* d_in, const int* in_sizes, int n_in,
                              void* d_out, int out_size, void* d_ws, size_t ws_size,
                              hipStream_t stream) {
    const float* inp = (const float*)d_in[0];
    const float* tar = (const float*)d_in[1];
    float* out = (float*)d_out;
    float* ws  = (float*)d_ws;

    float* s1 = ws;                       // 31104
    float* s2 = s1 + 31104;               // 7776
    float* gf = s2 + 7776;                // 2*14460*28 = 809760
    float* m  = gf + 809760;              // 2*2304*28 = 129024
    float* pv = m  + 129024;              // 4608*28 = 129024
    int*   pi = (int*)(pv + 129024);      // 129024
    float* lp = (float*)(pi + 129024);    // 18

    bicubic_k <<<(38880 + 255) / 256, 256, 0, stream>>>(tar, s1, s2);
    build_gf_k<<<(28920 + 255) / 256, 256, 0, stream>>>(tar, s1, s2, gf);
    build_m_k <<<(4608  + 255) / 256, 256, 0, stream>>>(inp, tar, m);
    argmin_k  <<<dim3(GSPLIT, 72), 256, 0, stream>>>(gf, m, pv, pi);
    finalize_k<<<18, 256, 0, stream>>>(gf, pv, pi, inp, out, lp);
    sum_k     <<<1, 64, 0, stream>>>(lp, out);
}

// Round 3
// 104.715 us; speedup vs baseline: 1.0711x; 1.0392x over previous
//
#include <hip/hip_runtime.h>
#include <math.h>

#define A_CUBIC (-0.75f)
#define NB 2
#define NC 3
#define HH 144
#define NPB 2304      // patches per batch (48*48)
#define GG 14460      // database patches per batch
#define DD 27
#define DP 28         // padded row stride; row[27] holds gn (for gf) or -1 (for m)
#define GSPLIT 48
#define GTILE 302     // ceil(14460/48)

__constant__ int c_seg_start[15] = {0,2209,2738,2859,5068,5597,5718,7927,8456,8577,10786,11315,11436,13740,14316};
__constant__ int c_seg_gw[15]    = {47,23,11, 47,23,11, 47,23,11, 47,23,11, 48,24,12};
__constant__ int c_seg_oy[15]    = {1,1,1, 1,1,1, 2,2,2, 2,2,2, 0,0,0};
__constant__ int c_seg_ox[15]    = {1,1,1, 2,2,2, 1,1,1, 2,2,2, 0,0,0};
__constant__ int c_seg_src[15]   = {0,1,2, 0,1,2, 0,1,2, 0,1,2, 0,1,2};

__device__ __forceinline__ float cubicw(float t) {
    float at = fabsf(t);
    if (at <= 1.0f) return ((A_CUBIC + 2.0f) * at - (A_CUBIC + 3.0f)) * at * at + 1.0f;
    if (at < 2.0f)  return A_CUBIC * (((at - 5.0f) * at + 8.0f) * at - 4.0f);
    return 0.0f;
}

// K1: bicubic downscale tar -> s1 (72x72), s2 (36x36), PLUS m-row build (fused).
__global__ void prep_k(const float* __restrict__ tar, const float* __restrict__ inp,
                       float* __restrict__ s1, float* __restrict__ s2,
                       float* __restrict__ m) {
    int t = blockIdx.x * 256 + threadIdx.x;
    const int total1 = NB * NC * 72 * 72;
    const int total2 = NB * NC * 36 * 36;
    if (t < total1 + total2) {
        float* dst; int O; int idx;
        if (t < total1) { dst = s1; O = 72; idx = t; }
        else            { dst = s2; O = 36; idx = t - total1; }
        int x  = idx % O;
        int y  = (idx / O) % O;
        int bc = idx / (O * O);
        const float* src = tar + (size_t)bc * HH * HH;
        float scale = (float)(143.0 / (double)(O - 1));
        float fy = (float)y * scale;
        float iyf = floorf(fy); float fry = fy - iyf; int iy = (int)iyf;
        float fx = (float)x * scale;
        float ixf = floorf(fx); float frx = fx - ixf; int ix = (int)ixf;
        float wy[4], wx[4];
        #pragma unroll
        for (int d = 0; d < 4; ++d) {
            wy[d] = cubicw(fry - (float)(d - 1));
            wx[d] = cubicw(frx - (float)(d - 1));
        }
        float acc = 0.0f;
        #pragma unroll
        for (int dx = 0; dx < 4; ++dx) {
            int cx = min(max(ix - 1 + dx, 0), HH - 1);
            float inner = 0.0f;
            #pragma unroll
            for (int dy = 0; dy < 4; ++dy) {
                int cy = min(max(iy - 1 + dy, 0), HH - 1);
                inner += wy[dy] * src[cy * HH + cx];
            }
            acc += wx[dx] * inner;
        }
        dst[idx] = acc;
    } else {
        int u = t - (total1 + total2);
        if (u >= NB * NPB) return;
        int b = u / NPB, n = u % NPB;
        int hc = n / 48, wc = n % 48;
        const float* ib = inp + (size_t)b * NC * HH * HH;
        const float* tb = tar + (size_t)b * NC * HH * HH;
        float* row = m + (size_t)u * DP;
        #pragma unroll
        for (int c = 0; c < 3; ++c)
            #pragma unroll
            for (int dy = 0; dy < 3; ++dy)
                #pragma unroll
                for (int dx = 0; dx < 3; ++dx) {
                    int off = (c * HH + hc * 3 + dy) * HH + wc * 3 + dx;
                    row[(c * 3 + dy) * 3 + dx] = ib[off] + tb[off];
                }
        row[27] = -1.0f;
    }
}

// K2: build gf database rows [B*G][28]; row[27] = |g|^2
__global__ void build_gf_k(const float* __restrict__ tar, const float* __restrict__ s1,
                           const float* __restrict__ s2, float* __restrict__ gf) {
    int t = blockIdx.x * 256 + threadIdx.x;
    if (t >= NB * GG) return;
    int b = t / GG, g = t % GG;
    int s = 0;
    #pragma unroll
    for (int k = 1; k < 15; ++k) if (g >= c_seg_start[k]) s = k;
    int p  = g - c_seg_start[s];
    int gw = c_seg_gw[s];
    int hc = p / gw, wc = p % gw;
    int oy = c_seg_oy[s], ox = c_seg_ox[s];
    int srci = c_seg_src[s];
    const float* img; int sz;
    if (srci == 0)      { img = tar; sz = 144; }
    else if (srci == 1) { img = s1;  sz = 72;  }
    else                { img = s2;  sz = 36;  }
    const float* base = img + (size_t)b * NC * sz * sz;
    int y0 = oy + hc * 3, x0 = ox + wc * 3;
    float acc = 0.0f;
    float* row = gf + (size_t)t * DP;
    #pragma unroll
    for (int c = 0; c < 3; ++c)
        #pragma unroll
        for (int dy = 0; dy < 3; ++dy)
            #pragma unroll
            for (int dx = 0; dx < 3; ++dx) {
                float v = base[((size_t)c * sz + y0 + dy) * sz + x0 + dx];
                row[(c * 3 + dy) * 3 + dx] = v;
                acc = fmaf(v, v, acc);
            }
    row[27] = acc;
}

// K4: per-thread n, ARGMAX over a g-tile of dot28(m, g). g-row loads are
// wave-uniform addresses into read-only memory -> compiler emits s_load,
// FMAs become v_fmac(vdst, sgpr, vgpr). No LDS, no syncthreads.
__global__ __launch_bounds__(256, 8) void argmin_k(
        const float* __restrict__ gf, const float* __restrict__ m,
        float* __restrict__ pv, int* __restrict__ pi) {
    int tid = threadIdx.x;
    int nblk = blockIdx.y;              // 0..17 (256 n each)
    int b  = nblk / 9;
    int nn = (size_t)nblk * 256 + tid;  // global n index (b*NPB + n)
    const float4* mrow = (const float4*)(m + (size_t)nn * DP);
    float4 mr[7];
    #pragma unroll
    for (int i = 0; i < 7; ++i) mr[i] = mrow[i];
    int g0 = blockIdx.x * GTILE;
    int g1 = min(g0 + GTILE, GG);
    const float* gfb = gf + (size_t)b * GG * DP;
    float bv = -3.0e38f; int bi = 0;
    #pragma unroll 2
    for (int g = g0; g < g1; ++g) {
        const float* gr = gfb + (size_t)g * DP;   // wave-uniform address
        float a0 = 0.0f, a1 = 0.0f;
        a0 = fmaf(mr[0].x, gr[0],  a0); a1 = fmaf(mr[0].y, gr[1],  a1);
        a0 = fmaf(mr[0].z, gr[2],  a0); a1 = fmaf(mr[0].w, gr[3],  a1);
        a0 = fmaf(mr[1].x, gr[4],  a0); a1 = fmaf(mr[1].y, gr[5],  a1);
        a0 = fmaf(mr[1].z, gr[6],  a0); a1 = fmaf(mr[1].w, gr[7],  a1);
        a0 = fmaf(mr[2].x, gr[8],  a0); a1 = fmaf(mr[2].y, gr[9],  a1);
        a0 = fmaf(mr[2].z, gr[10], a0); a1 = fmaf(mr[2].w, gr[11], a1);
        a0 = fmaf(mr[3].x, gr[12], a0); a1 = fmaf(mr[3].y, gr[13], a1);
        a0 = fmaf(mr[3].z, gr[14], a0); a1 = fmaf(mr[3].w, gr[15], a1);
        a0 = fmaf(mr[4].x, gr[16], a0); a1 = fmaf(mr[4].y, gr[17], a1);
        a0 = fmaf(mr[4].z, gr[18], a0); a1 = fmaf(mr[4].w, gr[19], a1);
        a0 = fmaf(mr[5].x, gr[20], a0); a1 = fmaf(mr[5].y, gr[21], a1);
        a0 = fmaf(mr[5].z, gr[22], a0); a1 = fmaf(mr[5].w, gr[23], a1);
        a0 = fmaf(mr[6].x, gr[24], a0); a1 = fmaf(mr[6].y, gr[25], a1);
        a0 = fmaf(mr[6].z, gr[26], a0); a1 = fmaf(mr[6].w, gr[27], a1);
        float s = a0 + a1;
        // g strictly increases -> strict > keeps first (lowest g) max
        if (s > bv) { bv = s; bi = g; }
    }
    size_t o = (size_t)nn * GSPLIT + blockIdx.x;
    pv[o] = bv; pi[o] = bi;
}

// K5: final argmax over g-tiles, gather sel, fold to image, block-partial L1 sums
__global__ void finalize_k(const float* __restrict__ gf, const float* __restrict__ pv,
                           const int* __restrict__ pi, const float* __restrict__ inp,
                           float* __restrict__ out, float* __restrict__ lpart) {
    __shared__ float red[256];
    int t = blockIdx.x * 256 + threadIdx.x;
    float lsum = 0.0f;
    if (t < NB * NPB) {
        int b = t / NPB, n = t % NPB;
        float bv = -3.0e38f; int bi = 0x7fffffff;
        #pragma unroll
        for (int s = 0; s < GSPLIT; ++s) {
            float v = pv[(size_t)t * GSPLIT + s];
            int   i = pi[(size_t)t * GSPLIT + s];
            if (v > bv || (v == bv && i < bi)) { bv = v; bi = i; }
        }
        int hc = n / 48, wc = n % 48;
        const float* grow = gf + ((size_t)b * GG + bi) * DP;
        const float* ib   = inp + (size_t)b * NC * HH * HH;
        float* sel = out + 1 + (size_t)b * NC * HH * HH;
        #pragma unroll
        for (int c = 0; c < 3; ++c)
            #pragma unroll
            for (int dy = 0; dy < 3; ++dy)
                #pragma unroll
                for (int dx = 0; dx < 3; ++dx) {
                    int d = (c * 3 + dy) * 3 + dx;
                    float sv = grow[d];
                    int off = (c * HH + hc * 3 + dy) * HH + wc * 3 + dx;
                    sel[off] = sv;
                    lsum += fabsf(ib[off] - sv);
                }
    }
    red[threadIdx.x] = lsum;
    __syncthreads();
    for (int s = 128; s > 0; s >>= 1) {
        if (threadIdx.x < s) red[threadIdx.x] += red[threadIdx.x + s];
        __syncthreads();
    }
    if (threadIdx.x == 0) lpart[blockIdx.x] = red[0];
}

// K6: scalar loss mean
__global__ void sum_k(const float* __restrict__ lpart, float* __restrict__ out) {
    if (threadIdx.x == 0) {
        float s = 0.0f;
        for (int i = 0; i < 18; ++i) s += lpart[i];
        out[0] = s * (1.0f / 124416.0f);
    }
}

extern "C" void kernel_launch(void* const* d_in, const int* in_sizes, int n_in,
                              void* d_out, int out_size, void* d_ws, size_t ws_size,
                              hipStream_t stream) {
    const float* inp = (const float*)d_in[0];
    const float* tar = (const float*)d_in[1];
    float* out = (float*)d_out;
    float* ws  = (float*)d_ws;

    float* s1 = ws;                       // 31104
    float* s2 = s1 + 31104;               // 7776
    float* gf = s2 + 7776;                // 2*14460*28 = 809760
    float* m  = gf + 809760;              // 2*2304*28 = 129024
    float* pv = m  + 129024;              // 4608*48 = 221184
    int*   pi = (int*)(pv + 221184);      // 221184
    float* lp = (float*)(pi + 221184);    // 18

    prep_k    <<<(43488 + 255) / 256, 256, 0, stream>>>(tar, inp, s1, s2, m);
    build_gf_k<<<(28920 + 255) / 256, 256, 0, stream>>>(tar, s1, s2, gf);
    argmin_k  <<<dim3(GSPLIT, 18), 256, 0, stream>>>(gf, m, pv, pi);
    finalize_k<<<18, 256, 0, stream>>>(gf, pv, pi, inp, out, lp);
    sum_k     <<<1, 64, 0, stream>>>(lp, out);
}

// Round 4
// 68.664 us; speedup vs baseline: 1.6334x; 1.5250x over previous
//
#include <hip/hip_runtime.h>
#include <math.h>

#define A_CUBIC (-0.75f)
#define NB 2
#define NC 3
#define HH 144
#define NPB 2304      // patches per batch (48*48)
#define GG 14460      // database patches per batch
#define DD 27
#define DP 28         // padded row stride; row[27] holds gn (for gf) or -1 (for m)
#define GSPLIT 112
#define GTILE 130     // ceil(14460/112)

typedef float v2f __attribute__((ext_vector_type(2)));

__constant__ int c_seg_start[15] = {0,2209,2738,2859,5068,5597,5718,7927,8456,8577,10786,11315,11436,13740,14316};
__constant__ int c_seg_gw[15]    = {47,23,11, 47,23,11, 47,23,11, 47,23,11, 48,24,12};
__constant__ int c_seg_oy[15]    = {1,1,1, 1,1,1, 2,2,2, 2,2,2, 0,0,0};
__constant__ int c_seg_ox[15]    = {1,1,1, 2,2,2, 1,1,1, 2,2,2, 0,0,0};
__constant__ int c_seg_src[15]   = {0,1,2, 0,1,2, 0,1,2, 0,1,2, 0,1,2};

__device__ __forceinline__ float cubicw(float t) {
    float at = fabsf(t);
    if (at <= 1.0f) return ((A_CUBIC + 2.0f) * at - (A_CUBIC + 3.0f)) * at * at + 1.0f;
    if (at < 2.0f)  return A_CUBIC * (((at - 5.0f) * at + 8.0f) * at - 4.0f);
    return 0.0f;
}

// K1: bicubic downscale tar -> s1 (72x72), s2 (36x36), PLUS m-row build + best init.
__global__ void prep_k(const float* __restrict__ tar, const float* __restrict__ inp,
                       float* __restrict__ s1, float* __restrict__ s2,
                       float* __restrict__ m, unsigned long long* __restrict__ best) {
    int t = blockIdx.x * 256 + threadIdx.x;
    const int total1 = NB * NC * 72 * 72;
    const int total2 = NB * NC * 36 * 36;
    if (t < total1 + total2) {
        float* dst; int O; int idx;
        if (t < total1) { dst = s1; O = 72; idx = t; }
        else            { dst = s2; O = 36; idx = t - total1; }
        int x  = idx % O;
        int y  = (idx / O) % O;
        int bc = idx / (O * O);
        const float* src = tar + (size_t)bc * HH * HH;
        float scale = (float)(143.0 / (double)(O - 1));
        float fy = (float)y * scale;
        float iyf = floorf(fy); float fry = fy - iyf; int iy = (int)iyf;
        float fx = (float)x * scale;
        float ixf = floorf(fx); float frx = fx - ixf; int ix = (int)ixf;
        float wy[4], wx[4];
        #pragma unroll
        for (int d = 0; d < 4; ++d) {
            wy[d] = cubicw(fry - (float)(d - 1));
            wx[d] = cubicw(frx - (float)(d - 1));
        }
        float acc = 0.0f;
        #pragma unroll
        for (int dx = 0; dx < 4; ++dx) {
            int cx = min(max(ix - 1 + dx, 0), HH - 1);
            float inner = 0.0f;
            #pragma unroll
            for (int dy = 0; dy < 4; ++dy) {
                int cy = min(max(iy - 1 + dy, 0), HH - 1);
                inner += wy[dy] * src[cy * HH + cx];
            }
            acc += wx[dx] * inner;
        }
        dst[idx] = acc;
    } else {
        int u = t - (total1 + total2);
        if (u >= NB * NPB) return;
        int b = u / NPB, n = u % NPB;
        int hc = n / 48, wc = n % 48;
        const float* ib = inp + (size_t)b * NC * HH * HH;
        const float* tb = tar + (size_t)b * NC * HH * HH;
        float* row = m + (size_t)u * DP;
        #pragma unroll
        for (int c = 0; c < 3; ++c)
            #pragma unroll
            for (int dy = 0; dy < 3; ++dy)
                #pragma unroll
                for (int dx = 0; dx < 3; ++dx) {
                    int off = (c * HH + hc * 3 + dy) * HH + wc * 3 + dx;
                    row[(c * 3 + dy) * 3 + dx] = ib[off] + tb[off];
                }
        row[27] = -1.0f;
        best[u] = 0ULL;
    }
}

// K2: build gf database rows [B*G][28]; row[27] = |g|^2
__global__ void build_gf_k(const float* __restrict__ tar, const float* __restrict__ s1,
                           const float* __restrict__ s2, float* __restrict__ gf) {
    int t = blockIdx.x * 256 + threadIdx.x;
    if (t >= NB * GG) return;
    int b = t / GG, g = t % GG;
    int s = 0;
    #pragma unroll
    for (int k = 1; k < 15; ++k) if (g >= c_seg_start[k]) s = k;
    int p  = g - c_seg_start[s];
    int gw = c_seg_gw[s];
    int hc = p / gw, wc = p % gw;
    int oy = c_seg_oy[s], ox = c_seg_ox[s];
    int srci = c_seg_src[s];
    const float* img; int sz;
    if (srci == 0)      { img = tar; sz = 144; }
    else if (srci == 1) { img = s1;  sz = 72;  }
    else                { img = s2;  sz = 36;  }
    const float* base = img + (size_t)b * NC * sz * sz;
    int y0 = oy + hc * 3, x0 = ox + wc * 3;
    float acc = 0.0f;
    float* row = gf + (size_t)t * DP;
    #pragma unroll
    for (int c = 0; c < 3; ++c)
        #pragma unroll
        for (int dy = 0; dy < 3; ++dy)
            #pragma unroll
            for (int dx = 0; dx < 3; ++dx) {
                float v = base[((size_t)c * sz + y0 + dy) * sz + x0 + dx];
                row[(c * 3 + dy) * 3 + dx] = v;
                acc = fmaf(v, v, acc);
            }
    row[27] = acc;
}

__device__ __forceinline__ float dot28(const v2f mr[14], const v2f r[14]) {
    v2f a0 = {0.0f, 0.0f}, a1 = {0.0f, 0.0f};
    #pragma unroll
    for (int i = 0; i < 14; i += 2) {
        a0 = __builtin_elementwise_fma(mr[i],     r[i],     a0);
        a1 = __builtin_elementwise_fma(mr[i + 1], r[i + 1], a1);
    }
    v2f t = a0 + a1;
    return t.x + t.y;
}

// K4: per-thread n, argmax over a g-tile of dot28(m, g) = m.g - gn.
// g-rows come in via wave-uniform s_loads (SGPR ping-pong double buffer);
// FMAs are packed v_pk_fma_f32. Result via one packed-u64 atomicMax per tile.
__global__ __launch_bounds__(256, 8) void argmin_k(
        const float* __restrict__ gf, const float* __restrict__ m,
        unsigned long long* __restrict__ best) {
    int tid = threadIdx.x;
    int nblk = blockIdx.y;              // 0..17 (256 n each)
    int b  = nblk / 9;
    int nn = nblk * 256 + tid;          // global n index (b*NPB + n)
    const v2f* mrow = (const v2f*)(m + (size_t)nn * DP);
    v2f mr[14];
    #pragma unroll
    for (int i = 0; i < 14; ++i) mr[i] = mrow[i];
    int g0 = blockIdx.x * GTILE;
    int g1 = min(g0 + GTILE, GG);
    const float* gfb = gf + (size_t)b * GG * DP;
    float bv = -3.0e38f; int bi = 0;

    v2f A[14], B[14];
    {
        const v2f* p = (const v2f*)(gfb + (size_t)g0 * DP);
        #pragma unroll
        for (int i = 0; i < 14; ++i) A[i] = p[i];
    }
    int g = g0;
    for (; g + 1 < g1; g += 2) {
        {   // prefetch row g+1
            const v2f* p = (const v2f*)(gfb + (size_t)(g + 1) * DP);
            #pragma unroll
            for (int i = 0; i < 14; ++i) B[i] = p[i];
        }
        float s = dot28(mr, A);
        if (s > bv) { bv = s; bi = g; }       // strict >: keeps first max
        {   // prefetch row g+2 (may overread 1 row; lands in ws, harmless)
            const v2f* p = (const v2f*)(gfb + (size_t)(g + 2) * DP);
            #pragma unroll
            for (int i = 0; i < 14; ++i) A[i] = p[i];
        }
        float s2 = dot28(mr, B);
        if (s2 > bv) { bv = s2; bi = g + 1; }
    }
    if (g < g1) {
        float s = dot28(mr, A);
        if (s > bv) { bv = s; bi = g; }
    }
    // monotonic float encoding; low word ~g so equal scores prefer smaller g
    unsigned u = __float_as_uint(bv);
    u ^= (unsigned)(((int)u >> 31)) | 0x80000000u;
    unsigned long long packed = ((unsigned long long)u << 32) | (unsigned)(~bi);
    atomicMax(&best[nn], packed);
}

// K5: decode best, gather sel, fold to image, block-partial L1 sums
__global__ void finalize_k(const float* __restrict__ gf,
                           const unsigned long long* __restrict__ best,
                           const float* __restrict__ inp,
                           float* __restrict__ out, float* __restrict__ lpart) {
    __shared__ float red[256];
    int t = blockIdx.x * 256 + threadIdx.x;
    float lsum = 0.0f;
    if (t < NB * NPB) {
        int b = t / NPB, n = t % NPB;
        unsigned long long pk = best[t];
        int bi = (int)(~(unsigned)(pk & 0xFFFFFFFFull));
        int hc = n / 48, wc = n % 48;
        const float* grow = gf + ((size_t)b * GG + bi) * DP;
        const float* ib   = inp + (size_t)b * NC * HH * HH;
        float* sel = out + 1 + (size_t)b * NC * HH * HH;
        #pragma unroll
        for (int c = 0; c < 3; ++c)
            #pragma unroll
            for (int dy = 0; dy < 3; ++dy)
                #pragma unroll
                for (int dx = 0; dx < 3; ++dx) {
                    int d = (c * 3 + dy) * 3 + dx;
                    float sv = grow[d];
                    int off = (c * HH + hc * 3 + dy) * HH + wc * 3 + dx;
                    sel[off] = sv;
                    lsum += fabsf(ib[off] - sv);
                }
    }
    red[threadIdx.x] = lsum;
    __syncthreads();
    for (int s = 128; s > 0; s >>= 1) {
        if (threadIdx.x < s) red[threadIdx.x] += red[threadIdx.x + s];
        __syncthreads();
    }
    if (threadIdx.x == 0) lpart[blockIdx.x] = red[0];
}

// K6: scalar loss mean
__global__ void sum_k(const float* __restrict__ lpart, float* __restrict__ out) {
    if (threadIdx.x == 0) {
        float s = 0.0f;
        for (int i = 0; i < 18; ++i) s += lpart[i];
        out[0] = s * (1.0f / 124416.0f);
    }
}

extern "C" void kernel_launch(void* const* d_in, const int* in_sizes, int n_in,
                              void* d_out, int out_size, void* d_ws, size_t ws_size,
                              hipStream_t stream) {
    const float* inp = (const float*)d_in[0];
    const float* tar = (const float*)d_in[1];
    float* out = (float*)d_out;
    float* ws  = (float*)d_ws;

    float* s1 = ws;                       // 31104
    float* s2 = s1 + 31104;               // 7776
    float* gf = s2 + 7776;                // 2*14460*28 = 809760
    float* m  = gf + 809760;              // 2*2304*28 = 129024
    unsigned long long* best = (unsigned long long*)(m + 129024);  // 4608 u64 (8B-aligned)
    float* lp = (float*)(best + 4608);    // 18

    prep_k    <<<(43488 + 255) / 256, 256, 0, stream>>>(tar, inp, s1, s2, m, best);
    build_gf_k<<<(28920 + 255) / 256, 256, 0, stream>>>(tar, s1, s2, gf);
    argmin_k  <<<dim3(GSPLIT, 18), 256, 0, stream>>>(gf, m, best);
    finalize_k<<<18, 256, 0, stream>>>(gf, best, inp, out, lp);
    sum_k     <<<1, 64, 0, stream>>>(lp, out);
}

// Round 5
// 66.492 us; speedup vs baseline: 1.6868x; 1.0327x over previous
//
#include <hip/hip_runtime.h>
#include <math.h>

#define A_CUBIC (-0.75f)
#define NB 2
#define NC 3
#define HH 144
#define NPB 2304      // patches per batch (48*48)
#define GG 14460      // database patches per batch
#define DD 27
#define DP 28         // padded row stride; row[27] holds gn (for gf) or -1 (for m)
#define GSPLIT 128
#define GTILE 113     // ceil(14460/128)

typedef float v2f __attribute__((ext_vector_type(2)));

__constant__ int c_seg_start[15] = {0,2209,2738,2859,5068,5597,5718,7927,8456,8577,10786,11315,11436,13740,14316};
__constant__ int c_seg_gw[15]    = {47,23,11, 47,23,11, 47,23,11, 47,23,11, 48,24,12};
__constant__ int c_seg_oy[15]    = {1,1,1, 1,1,1, 2,2,2, 2,2,2, 0,0,0};
__constant__ int c_seg_ox[15]    = {1,1,1, 2,2,2, 1,1,1, 2,2,2, 0,0,0};
__constant__ int c_seg_src[15]   = {0,1,2, 0,1,2, 0,1,2, 0,1,2, 0,1,2};

__device__ __forceinline__ float cubicw(float t) {
    float at = fabsf(t);
    if (at <= 1.0f) return ((A_CUBIC + 2.0f) * at - (A_CUBIC + 3.0f)) * at * at + 1.0f;
    if (at < 2.0f)  return A_CUBIC * (((at - 5.0f) * at + 8.0f) * at - 4.0f);
    return 0.0f;
}

// K1: bicubic downscale tar -> s1 (72x72), s2 (36x36), PLUS m-row build + best init.
__global__ void prep_k(const float* __restrict__ tar, const float* __restrict__ inp,
                       float* __restrict__ s1, float* __restrict__ s2,
                       float* __restrict__ m, unsigned long long* __restrict__ best) {
    int t = blockIdx.x * 256 + threadIdx.x;
    const int total1 = NB * NC * 72 * 72;
    const int total2 = NB * NC * 36 * 36;
    if (t < total1 + total2) {
        float* dst; int O; int idx;
        if (t < total1) { dst = s1; O = 72; idx = t; }
        else            { dst = s2; O = 36; idx = t - total1; }
        int x  = idx % O;
        int y  = (idx / O) % O;
        int bc = idx / (O * O);
        const float* src = tar + (size_t)bc * HH * HH;
        float scale = (float)(143.0 / (double)(O - 1));
        float fy = (float)y * scale;
        float iyf = floorf(fy); float fry = fy - iyf; int iy = (int)iyf;
        float fx = (float)x * scale;
        float ixf = floorf(fx); float frx = fx - ixf; int ix = (int)ixf;
        float wy[4], wx[4];
        #pragma unroll
        for (int d = 0; d < 4; ++d) {
            wy[d] = cubicw(fry - (float)(d - 1));
            wx[d] = cubicw(frx - (float)(d - 1));
        }
        float acc = 0.0f;
        #pragma unroll
        for (int dx = 0; dx < 4; ++dx) {
            int cx = min(max(ix - 1 + dx, 0), HH - 1);
            float inner = 0.0f;
            #pragma unroll
            for (int dy = 0; dy < 4; ++dy) {
                int cy = min(max(iy - 1 + dy, 0), HH - 1);
                inner += wy[dy] * src[cy * HH + cx];
            }
            acc += wx[dx] * inner;
        }
        dst[idx] = acc;
    } else {
        int u = t - (total1 + total2);
        if (u >= NB * NPB) return;
        int b = u / NPB, n = u % NPB;
        int hc = n / 48, wc = n % 48;
        const float* ib = inp + (size_t)b * NC * HH * HH;
        const float* tb = tar + (size_t)b * NC * HH * HH;
        float* row = m + (size_t)u * DP;
        #pragma unroll
        for (int c = 0; c < 3; ++c)
            #pragma unroll
            for (int dy = 0; dy < 3; ++dy)
                #pragma unroll
                for (int dx = 0; dx < 3; ++dx) {
                    int off = (c * HH + hc * 3 + dy) * HH + wc * 3 + dx;
                    row[(c * 3 + dy) * 3 + dx] = ib[off] + tb[off];
                }
        row[27] = -1.0f;
        best[u] = 0ULL;
    }
}

// K2: build gf database rows [B*G][28]; row[27] = |g|^2
__global__ void build_gf_k(const float* __restrict__ tar, const float* __restrict__ s1,
                           const float* __restrict__ s2, float* __restrict__ gf) {
    int t = blockIdx.x * 256 + threadIdx.x;
    if (t >= NB * GG) return;
    int b = t / GG, g = t % GG;
    int s = 0;
    #pragma unroll
    for (int k = 1; k < 15; ++k) if (g >= c_seg_start[k]) s = k;
    int p  = g - c_seg_start[s];
    int gw = c_seg_gw[s];
    int hc = p / gw, wc = p % gw;
    int oy = c_seg_oy[s], ox = c_seg_ox[s];
    int srci = c_seg_src[s];
    const float* img; int sz;
    if (srci == 0)      { img = tar; sz = 144; }
    else if (srci == 1) { img = s1;  sz = 72;  }
    else                { img = s2;  sz = 36;  }
    const float* base = img + (size_t)b * NC * sz * sz;
    int y0 = oy + hc * 3, x0 = ox + wc * 3;
    float acc = 0.0f;
    float* row = gf + (size_t)t * DP;
    #pragma unroll
    for (int c = 0; c < 3; ++c)
        #pragma unroll
        for (int dy = 0; dy < 3; ++dy)
            #pragma unroll
            for (int dx = 0; dx < 3; ++dx) {
                float v = base[((size_t)c * sz + y0 + dy) * sz + x0 + dx];
                row[(c * 3 + dy) * 3 + dx] = v;
                acc = fmaf(v, v, acc);
            }
    row[27] = acc;
}

__device__ __forceinline__ void dot28x3(const v2f r0[14], const v2f r1[14], const v2f r2[14],
                                        const v2f gR[14], float& s0, float& s1, float& s2) {
    v2f a0 = {0.0f, 0.0f}, a1 = {0.0f, 0.0f}, a2 = {0.0f, 0.0f};
    #pragma unroll
    for (int i = 0; i < 14; ++i) {
        a0 = __builtin_elementwise_fma(r0[i], gR[i], a0);
        a1 = __builtin_elementwise_fma(r1[i], gR[i], a1);
        a2 = __builtin_elementwise_fma(r2[i], gR[i], a2);
    }
    s0 = a0.x + a0.y; s1 = a1.x + a1.y; s2 = a2.x + a2.y;
}

// K4: each thread owns 3 n-rows (84 floats of m in VGPRs); g-rows arrive via
// wave-uniform s_loads (SGPR ping-pong); each row feeds 42 packed FMAs.
__global__ __launch_bounds__(256, 4) void argmin_k(
        const float* __restrict__ gf, const float* __restrict__ m,
        unsigned long long* __restrict__ best) {
    int tid = threadIdx.x;
    int nb = blockIdx.y;                // 0..5, 768 n each
    int b  = nb / 3;
    int n0 = nb * 768 + tid;            // this thread's three n: n0, n0+256, n0+512
    const v2f* m0 = (const v2f*)(m + (size_t)n0 * DP);
    const v2f* m1 = (const v2f*)(m + (size_t)(n0 + 256) * DP);
    const v2f* m2 = (const v2f*)(m + (size_t)(n0 + 512) * DP);
    v2f r0[14], r1[14], r2[14];
    #pragma unroll
    for (int i = 0; i < 14; ++i) { r0[i] = m0[i]; r1[i] = m1[i]; r2[i] = m2[i]; }
    int g0 = blockIdx.x * GTILE;
    int g1 = min(g0 + GTILE, GG);
    const float* gfb = gf + (size_t)b * GG * DP;
    float bv0 = -3.0e38f, bv1 = -3.0e38f, bv2 = -3.0e38f;
    int   bi0 = 0,        bi1 = 0,        bi2 = 0;

    v2f A[14], B[14];
    {
        const v2f* p = (const v2f*)(gfb + (size_t)g0 * DP);
        #pragma unroll
        for (int i = 0; i < 14; ++i) A[i] = p[i];
    }
    int g = g0;
    for (; g + 1 < g1; g += 2) {
        {   // prefetch row g+1
            const v2f* p = (const v2f*)(gfb + (size_t)(g + 1) * DP);
            #pragma unroll
            for (int i = 0; i < 14; ++i) B[i] = p[i];
        }
        float s0, s1, s2;
        dot28x3(r0, r1, r2, A, s0, s1, s2);
        if (s0 > bv0) { bv0 = s0; bi0 = g; }   // strict >: keeps first max
        if (s1 > bv1) { bv1 = s1; bi1 = g; }
        if (s2 > bv2) { bv2 = s2; bi2 = g; }
        {   // prefetch row g+2 (overreads ≤1 row past gf; lands in ws, harmless)
            const v2f* p = (const v2f*)(gfb + (size_t)(g + 2) * DP);
            #pragma unroll
            for (int i = 0; i < 14; ++i) A[i] = p[i];
        }
        dot28x3(r0, r1, r2, B, s0, s1, s2);
        if (s0 > bv0) { bv0 = s0; bi0 = g + 1; }
        if (s1 > bv1) { bv1 = s1; bi1 = g + 1; }
        if (s2 > bv2) { bv2 = s2; bi2 = g + 1; }
    }
    if (g < g1) {
        float s0, s1, s2;
        dot28x3(r0, r1, r2, A, s0, s1, s2);
        if (s0 > bv0) { bv0 = s0; bi0 = g; }
        if (s1 > bv1) { bv1 = s1; bi1 = g; }
        if (s2 > bv2) { bv2 = s2; bi2 = g; }
    }
    // monotonic float encoding; low word ~g so equal scores prefer smaller g
    unsigned u0 = __float_as_uint(bv0); u0 ^= (unsigned)(((int)u0 >> 31)) | 0x80000000u;
    unsigned u1 = __float_as_uint(bv1); u1 ^= (unsigned)(((int)u1 >> 31)) | 0x80000000u;
    unsigned u2 = __float_as_uint(bv2); u2 ^= (unsigned)(((int)u2 >> 31)) | 0x80000000u;
    atomicMax(&best[n0],       ((unsigned long long)u0 << 32) | (unsigned)(~bi0));
    atomicMax(&best[n0 + 256], ((unsigned long long)u1 << 32) | (unsigned)(~bi1));
    atomicMax(&best[n0 + 512], ((unsigned long long)u2 << 32) | (unsigned)(~bi2));
}

// K5: decode best, gather sel, fold to image, block-partial L1 sums
__global__ void finalize_k(const float* __restrict__ gf,
                           const unsigned long long* __restrict__ best,
                           const float* __restrict__ inp,
                           float* __restrict__ out, float* __restrict__ lpart) {
    __shared__ float red[256];
    int t = blockIdx.x * 256 + threadIdx.x;
    float lsum = 0.0f;
    if (t < NB * NPB) {
        int b = t / NPB, n = t % NPB;
        unsigned long long pk = best[t];
        int bi = (int)(~(unsigned)(pk & 0xFFFFFFFFull));
        int hc = n / 48, wc = n % 48;
        const float* grow = gf + ((size_t)b * GG + bi) * DP;
        const float* ib   = inp + (size_t)b * NC * HH * HH;
        float* sel = out + 1 + (size_t)b * NC * HH * HH;
        #pragma unroll
        for (int c = 0; c < 3; ++c)
            #pragma unroll
            for (int dy = 0; dy < 3; ++dy)
                #pragma unroll
                for (int dx = 0; dx < 3; ++dx) {
                    int d = (c * 3 + dy) * 3 + dx;
                    float sv = grow[d];
                    int off = (c * HH + hc * 3 + dy) * HH + wc * 3 + dx;
                    sel[off] = sv;
                    lsum += fabsf(ib[off] - sv);
                }
    }
    red[threadIdx.x] = lsum;
    __syncthreads();
    for (int s = 128; s > 0; s >>= 1) {
        if (threadIdx.x < s) red[threadIdx.x] += red[threadIdx.x + s];
        __syncthreads();
    }
    if (threadIdx.x == 0) lpart[blockIdx.x] = red[0];
}

// K6: scalar loss mean
__global__ void sum_k(const float* __restrict__ lpart, float* __restrict__ out) {
    if (threadIdx.x == 0) {
        float s = 0.0f;
        for (int i = 0; i < 18; ++i) s += lpart[i];
        out[0] = s * (1.0f / 124416.0f);
    }
}

extern "C" void kernel_launch(void* const* d_in, const int* in_sizes, int n_in,
                              void* d_out, int out_size, void* d_ws, size_t ws_size,
                              hipStream_t stream) {
    const float* inp = (const float*)d_in[0];
    const float* tar = (const float*)d_in[1];
    float* out = (float*)d_out;
    float* ws  = (float*)d_ws;

    float* s1 = ws;                       // 31104
    float* s2 = s1 + 31104;               // 7776
    float* gf = s2 + 7776;                // 2*14460*28 = 809760
    float* m  = gf + 809760;              // 2*2304*28 = 129024
    unsigned long long* best = (unsigned long long*)(m + 129024);  // 4608 u64
    float* lp = (float*)(best + 4608);    // 18

    prep_k    <<<(43488 + 255) / 256, 256, 0, stream>>>(tar, inp, s1, s2, m, best);
    build_gf_k<<<(28920 + 255) / 256, 256, 0, stream>>>(tar, s1, s2, gf);
    argmin_k  <<<dim3(GSPLIT, 6), 256, 0, stream>>>(gf, m, best);
    finalize_k<<<18, 256, 0, stream>>>(gf, best, inp, out, lp);
    sum_k     <<<1, 64, 0, stream>>>(lp, out);
}